// Round 9
// baseline (364.147 us; speedup 1.0000x reference)
//
#include <hip/hip_runtime.h>
#include <cstdint>
#include <cstddef>

// DenseCaps dynamic routing, MI355X. B=256, R=2048, NC=10, OUT=16, IN=8, 3 iters.
//
// R9: fix R8's register-residency failure (VGPR=128 < W(64)+acc(64)+temps
// -> compiler split W loads into dependent load-use chains; VALUBusy 34%,
// 2 blocks/CU gave only 2 waves/SIMD of latency cover).
//  - lane = (oq in [0,4), n in [0,16)): one route per wave, o in quarters.
//    W fragment 32 regs, acc[4b][4o] 16 regs, v-frag 16 regs -> ~95 total:
//    genuinely register-resident, 8-load cluster per route vs ~220 VALU.
//  - vsh LDS tile DELETED: each lane loads its v fragment from global
//    vsum once (160KB buffer, L2-hot after reduce_k).
//  - LDS = 16KB x-tile only -> __launch_bounds__(256,4): 4 blocks/CU,
//    4 waves/SIMD (2x R8's latency cover).
//  - grid 1024 = 64 rb x 16 bg; XCD-bijective map (rb = q*8+s, idx =
//    q*128+bg*8+s): per-XCD W slice 1.25MB, L2-resident, 16x reuse.
//  - unchanged verified pieces: slab + reduce_k (atomic-free s-reduction),
//    deferred logits b_k = b_in + dot(u, v0+..+v_{k-1}), DPP softmax.

#define B_   256
#define R_   2048
#define NC_  10

typedef __attribute__((ext_vector_type(4))) float f32x4;

// ---- DPP row reductions (16-lane rows; all lanes active) ----
template<int CTRL>
__device__ __forceinline__ float dpp_mov(float x){
  return __int_as_float(__builtin_amdgcn_update_dpp(
      0, __float_as_int(x), CTRL, 0xF, 0xF, true));
}
__device__ __forceinline__ float dmax16(float x){
  x = fmaxf(x, dpp_mov<0xB1>(x));    // quad_perm xor1
  x = fmaxf(x, dpp_mov<0x4E>(x));    // quad_perm xor2
  x = fmaxf(x, dpp_mov<0x141>(x));   // row_half_mirror
  x = fmaxf(x, dpp_mov<0x140>(x));   // row_mirror
  return x;
}
__device__ __forceinline__ float dsum16(float x){
  x += dpp_mov<0xB1>(x);
  x += dpp_mov<0x4E>(x);
  x += dpp_mov<0x141>(x);
  x += dpp_mov<0x140>(x);
  return x;
}
__device__ __forceinline__ float rsum16(float x){   // reduce kernel only
  x += __shfl_xor(x, 1, 16);
  x += __shfl_xor(x, 2, 16);
  x += __shfl_xor(x, 4, 16);
  x += __shfl_xor(x, 8, 16);
  return x;
}

// MODE 0: c = softmax(b_in)                      -> slab partial of s0
// MODE k: c = softmax(b_in + dot(u, vsum_{k-1})) -> slab partial of s_k
// MODE 3 additionally writes c to c_out.
// Block: 4 waves; owns 32 r x 16 b; wave w owns b-quad w (4 b's), walks
// all 32 routes. Lane: oq = lane>>4 (o-quarter), n = lane&15 (10 active).
template<int MODE>
__global__ __launch_bounds__(256, 4) void route_pass(
    const float* __restrict__ x,     // [256][2048][8]
    const float* __restrict__ W,     // [2048][8][160]
    const float* __restrict__ b_in,  // [2048][10]
    float*       __restrict__ c_out, // [256][2048][10]
    const float* __restrict__ vsum,  // [256][160]
    float*       __restrict__ slab)  // [64 rb][256 b][160]
{
  const int t   = threadIdx.x;
  // bijective XCD map: idx = q*128 + bg*8 + s; rb = q*8 + s -> all 16 bg
  // siblings of an rb land on XCD s (W slice 8 rb x 160KB = 1.25MB/XCD).
  const int idx = blockIdx.x;
  const int s_  = idx & 7;
  const int bg  = (idx >> 3) & 15;
  const int q_  = idx >> 7;
  const int rb  = q_ * 8 + s_;      // 0..63
  const int b0g = bg * 16;
  const int r0  = rb * 32;
  const int w    = t >> 6;
  const int lane = t & 63;
  const int oq   = lane >> 4;       // o-quarter 0..3
  const int n    = lane & 15;       // class lane (10 active)
  const int nn   = (n < NC_) ? n : (NC_ - 1);
  const int bw0  = w * 4;           // wave's b-quad within block

  __shared__ float xs[16 * 32 * 8];   // 16 KB  [bl][rl][8]

  // stage x tile (coalesced 1KB runs per b-row): 1024 f32x4
  for (int i2 = t; i2 < 1024; i2 += 256){
    int bl = i2 >> 6, rest = i2 & 63;
    ((f32x4*)xs)[i2] =
      *(const f32x4*)(x + ((size_t)(b0g + bl) * R_ + r0) * 8 + rest * 4);
  }
  __syncthreads();

  // v fragment per (bi): 4 floats each, loaded once from L2-hot vsum
  f32x4 vreg[4];
  if (MODE >= 1){
    #pragma unroll
    for (int bi = 0; bi < 4; ++bi)
      vreg[bi] = *(const f32x4*)(vsum + (size_t)(b0g + bw0 + bi) * 160
                                      + nn * 16 + oq * 4);
  }

  float acc[4][4];
  #pragma unroll
  for (int bi = 0; bi < 4; ++bi)
    #pragma unroll
    for (int j = 0; j < 4; ++j) acc[bi][j] = 0.f;

  #pragma unroll 1
  for (int rl = 0; rl < 32; ++rl){
    const int r = r0 + rl;
    // W fragment: 8 i x 4 o for this lane's (nn, oq) -> 32 regs, 8 loads
    f32x4 w8[8];
    {
      const float* wp = W + (size_t)r * 1280 + nn * 16 + oq * 4;
      #pragma unroll
      for (int i = 0; i < 8; ++i)
        w8[i] = *(const f32x4*)(wp + i * 160);
    }
    const float binr = b_in[r * NC_ + nn];
    float c0r = 0.f;
    if (MODE == 0){
      float bnew = (n < NC_) ? binr : -1e30f;
      float m = dmax16(bnew);
      float e = __expf(bnew - m);
      float su = dsum16(e);
      c0r = e / su;
    }

    #pragma unroll
    for (int bi = 0; bi < 4; ++bi){
      const f32x4* xp = (const f32x4*)(xs + ((bw0 + bi) * 32 + rl) * 8);
      f32x4 xa = xp[0], xb = xp[1];     // wave-broadcast reads
      float xr[8] = {xa[0], xa[1], xa[2], xa[3], xb[0], xb[1], xb[2], xb[3]};

      float u[4];
      #pragma unroll
      for (int j = 0; j < 4; ++j) u[j] = 0.f;
      #pragma unroll
      for (int i = 0; i < 8; ++i)
        #pragma unroll
        for (int j = 0; j < 4; ++j)
          u[j] = fmaf(xr[i], w8[i][j], u[j]);

      float c;
      if (MODE == 0){
        c = c0r;
      } else {
        float dp = 0.f;
        #pragma unroll
        for (int j = 0; j < 4; ++j) dp = fmaf(u[j], vreg[bi][j], dp);
        dp += __shfl_xor(dp, 16, 64);       // merge o-quarters
        dp += __shfl_xor(dp, 32, 64);
        float bnew = (n < NC_) ? (binr + dp) : -1e30f;
        float m = dmax16(bnew);
        float e = __expf(bnew - m);          // idle class lanes -> 0
        float su = dsum16(e);
        c = e / su;
        if (MODE == 3 && n < NC_ && oq == 0)
          c_out[((size_t)(b0g + bw0 + bi) * R_ + r) * NC_ + n] = c;
      }
      #pragma unroll
      for (int j = 0; j < 4; ++j) acc[bi][j] = fmaf(c, u[j], acc[bi][j]);
    }
  }

  // flush: lanes (oq, n<10) tile the 640B slab row exactly; no cross-lane
  // merge needed (each (b,n,o) owned by exactly one lane of one block).
  if (n < NC_){
    #pragma unroll
    for (int bi = 0; bi < 4; ++bi){
      float* dst = slab + ((size_t)rb * 256 + (b0g + bw0 + bi)) * 160
                        + n * 16 + oq * 4;
      f32x4 v4 = {acc[bi][0], acc[bi][1], acc[bi][2], acc[bi][3]};
      *(f32x4*)dst = v4;
    }
  }
}

// ---------- reduce: s = sum of 64 rb partials; v = squash(s);
// K==0: vsum = v; K<3: vsum += v; K==3: write v_out. One block per b.
__global__ __launch_bounds__(256) void reduce_k(const float* __restrict__ slab,
                                                float* __restrict__ vsum,
                                                float* __restrict__ vout,
                                                int K){
  const int b = blockIdx.x;
  const int t = threadIdx.x;
  if (t >= 160) return;
  const float* p = slab + (size_t)b * 160 + t;
  float s = 0.f;
  #pragma unroll 8
  for (int rc = 0; rc < 64; ++rc) s += p[(size_t)rc * 40960];
  float ss = rsum16(s * s);
  float v = (sqrtf(ss) / (1.f + ss + 1e-8f)) * s;
  if (K == 0)      vsum[b * 160 + t]  = v;
  else if (K < 3)  vsum[b * 160 + t] += v;
  else             vout[b * 160 + t]  = v;
}

extern "C" void kernel_launch(void* const* d_in, const int* in_sizes, int n_in,
                              void* d_out, int out_size, void* d_ws, size_t ws_size,
                              hipStream_t stream){
  const float* x    = (const float*)d_in[0];   // [256,2048,8]
  const float* W    = (const float*)d_in[1];   // [2048,8,160]
  const float* b_in = (const float*)d_in[2];   // [2048,10]
  float* out = (float*)d_out;
  float* out_v = out;                 // 40960 floats
  float* c_out = out + 40960;         // [B][R][NC] final coupling coeffs

  float* slab = (float*)d_ws;                  // 64*256*160*4 = 10.49 MB
  float* vsum = slab + (size_t)64 * 40960;     // 160 KB

  route_pass<0><<<1024, 256, 0, stream>>>(x, W, b_in, c_out, vsum, slab);
  reduce_k<<<256, 256, 0, stream>>>(slab, vsum, out_v, 0);
  route_pass<1><<<1024, 256, 0, stream>>>(x, W, b_in, c_out, vsum, slab);
  reduce_k<<<256, 256, 0, stream>>>(slab, vsum, out_v, 1);
  route_pass<2><<<1024, 256, 0, stream>>>(x, W, b_in, c_out, vsum, slab);
  reduce_k<<<256, 256, 0, stream>>>(slab, vsum, out_v, 2);
  route_pass<3><<<1024, 256, 0, stream>>>(x, W, b_in, c_out, vsum, slab);
  reduce_k<<<256, 256, 0, stream>>>(slab, vsum, out_v, 3);
}